// Round 2
// baseline (608.640 us; speedup 1.0000x reference)
//
#include <hip/hip_runtime.h>
#include <cstddef>
#include <cstdint>

typedef unsigned short u16;
typedef short s16x8 __attribute__((ext_vector_type(8)));
typedef float f32x4 __attribute__((ext_vector_type(4)));
typedef int   i32x4 __attribute__((ext_vector_type(4)));
typedef u16   u16x4 __attribute__((ext_vector_type(4)));

__device__ __forceinline__ float b2f(u16 u) {
  union { unsigned int i; float f; } v; v.i = ((unsigned int)u) << 16; return v.f;
}
__device__ __forceinline__ u16 f2b(float f) {
  union { float f; unsigned int i; } v; v.f = f;
  unsigned int r = v.i + 0x7fffu + ((v.i >> 16) & 1u);
  return (u16)(r >> 16);
}

// ---------------------------------------------------------------------------
// Transpose+cast the 6 fp32 weight matrices (256x256) -> bf16 WT[n][k].
// grid(6,32) x 256 thr.
// ---------------------------------------------------------------------------
__global__ __launch_bounds__(256) void transpose6(
    const float* __restrict__ w0, const float* __restrict__ w1,
    const float* __restrict__ w2, const float* __restrict__ w3,
    const float* __restrict__ w4, const float* __restrict__ w5,
    u16* __restrict__ wt)
{
  const float* src;
  switch (blockIdx.x) {
    case 0: src = w0; break; case 1: src = w1; break;
    case 2: src = w2; break; case 3: src = w3; break;
    case 4: src = w4; break; default: src = w5; break;
  }
  u16* dst = wt + (size_t)blockIdx.x * 65536;
  const int base = blockIdx.y * 2048;
  #pragma unroll
  for (int ii = 0; ii < 8; ++ii) {
    int i = base + ii * 256 + threadIdx.x;
    dst[i] = f2b(src[(i & 255) * 256 + (i >> 8)]);
  }
}

// ---------------------------------------------------------------------------
// FiLM precompute (fp32): emb = pos(256x256) @ W_emb(256x512) + b_emb
// shift = emb[:, :256], scale = emb[:, 256:]. grid 256 x 256 thr.
// ---------------------------------------------------------------------------
__global__ __launch_bounds__(256) void film_kernel(
    const float* __restrict__ pos, const float* __restrict__ Wemb,
    const float* __restrict__ bemb, float* __restrict__ shift,
    float* __restrict__ scale)
{
  __shared__ float prow[256];
  const int s = blockIdx.x, t = threadIdx.x;
  prow[t] = pos[s * 256 + t];
  __syncthreads();
  #pragma unroll
  for (int half = 0; half < 2; ++half) {
    const int c = half * 256 + t;
    float acc = bemb[c];
    for (int kk = 0; kk < 256; ++kk)
      acc = fmaf(prow[kk], Wemb[kk * 512 + c], acc);
    float* dst = half ? scale : shift;
    dst[s * 256 + t] = acc;
  }
}

// ---------------------------------------------------------------------------
// LayerNorm over f=256 per token (fp32 in, bf16 out); wave per token.
// If shift != nullptr also applies FiLM: ln*(scale+1)+shift (spos = token%256).
// grid 16384 x 256 thr.
// ---------------------------------------------------------------------------
__global__ __launch_bounds__(256) void ln_kernel(
    const float* __restrict__ x, const float* __restrict__ shift,
    const float* __restrict__ scale, const float* __restrict__ g,
    const float* __restrict__ b, u16* __restrict__ out)
{
  const int token = blockIdx.x * 4 + (threadIdx.x >> 6);
  const int lane = threadIdx.x & 63;
  f32x4 v = *(const f32x4*)(x + (size_t)token * 256 + lane * 4);
  float s  = v[0] + v[1] + v[2] + v[3];
  float s2 = v[0]*v[0] + v[1]*v[1] + v[2]*v[2] + v[3]*v[3];
  #pragma unroll
  for (int off = 32; off >= 1; off >>= 1) {
    s  += __shfl_xor(s, off);
    s2 += __shfl_xor(s2, off);
  }
  const float mean = s * 0.00390625f;
  const float var  = s2 * 0.00390625f - mean * mean;
  const float inv  = rsqrtf(var + 1e-5f);
  const int spos = token & 255;
  u16x4 o;
  #pragma unroll
  for (int i = 0; i < 4; ++i) {
    const int f = lane * 4 + i;
    float ln = (v[i] - mean) * inv * g[f] + b[f];
    if (shift) ln = ln * (scale[spos * 256 + f] + 1.0f) + shift[spos * 256 + f];
    o[i] = f2b(ln);
  }
  *(u16x4*)(out + (size_t)token * 256 + lane * 4) = o;
}

// ---------------------------------------------------------------------------
// GEMM: A(65536x256) bf16 @ WT[n][k] bf16.
// 128x128 block tile, BK=64, 4 waves, wave tile 64x64 (4x4 16x16x32 MFMA).
// modes: 0 = +bias, natural bf16 store [m][n]
//        1 = +bias, transposed-per-window bf16 store vT[w][n][m%256]
//        2 = fp32 residual: out_f = extra + coef[n]*(acc+bias)
//        3 = silu(acc) bf16 store
// grid (512, 2) x 256 thr.
// ---------------------------------------------------------------------------
__global__ __launch_bounds__(256) void gemm256(
    const u16* __restrict__ A, const u16* __restrict__ BT,
    const float* __restrict__ bias, const float* extra,
    const float* __restrict__ coef, u16* __restrict__ out_b,
    float* out_f, int mode)
{
  __shared__ __align__(16) u16 Alds[128][72];  // +8 pad
  __shared__ __align__(16) u16 Blds[128][72];
  const int m0 = blockIdx.x * 128;
  const int n0 = blockIdx.y * 128;
  const int t = threadIdx.x;
  const int wave = t >> 6, lane = t & 63;
  const int wm = (wave & 1) * 64, wn = (wave >> 1) * 64;
  const int lrow = lane & 15, lk = (lane >> 4) * 8;

  f32x4 acc[4][4];
  #pragma unroll
  for (int i = 0; i < 4; ++i)
    #pragma unroll
    for (int j = 0; j < 4; ++j)
      acc[i][j] = f32x4{0.f, 0.f, 0.f, 0.f};

  for (int k0 = 0; k0 < 256; k0 += 64) {
    #pragma unroll
    for (int i = 0; i < 4; ++i) {
      const int c = i * 256 + t;
      const int row = c >> 3, col = (c & 7) * 8;
      *(i32x4*)(&Alds[row][col]) = *(const i32x4*)(A  + (size_t)(m0 + row) * 256 + k0 + col);
      *(i32x4*)(&Blds[row][col]) = *(const i32x4*)(BT + (size_t)(n0 + row) * 256 + k0 + col);
    }
    __syncthreads();
    #pragma unroll
    for (int kk = 0; kk < 64; kk += 32) {
      s16x8 af[4], bf[4];
      #pragma unroll
      for (int mt = 0; mt < 4; ++mt) af[mt] = *(const s16x8*)(&Alds[wm + mt*16 + lrow][kk + lk]);
      #pragma unroll
      for (int nt = 0; nt < 4; ++nt) bf[nt] = *(const s16x8*)(&Blds[wn + nt*16 + lrow][kk + lk]);
      #pragma unroll
      for (int mt = 0; mt < 4; ++mt)
        #pragma unroll
        for (int nt = 0; nt < 4; ++nt)
          acc[mt][nt] = __builtin_amdgcn_mfma_f32_16x16x32_bf16(af[mt], bf[nt], acc[mt][nt], 0, 0, 0);
    }
    __syncthreads();
  }

  #pragma unroll
  for (int mt = 0; mt < 4; ++mt) {
    const int mb = m0 + wm + mt*16 + (lane >> 4) * 4;
    #pragma unroll
    for (int nt = 0; nt < 4; ++nt) {
      const int n = n0 + wn + nt*16 + lrow;
      const float bv = bias ? bias[n] : 0.0f;
      if (mode == 1) {
        u16x4 pk;
        #pragma unroll
        for (int r = 0; r < 4; ++r) pk[r] = f2b(acc[mt][nt][r] + bv);
        const int w = mb >> 8, ti = mb & 255;
        *(u16x4*)(out_b + (size_t)w * 65536 + (size_t)n * 256 + ti) = pk;
      } else {
        #pragma unroll
        for (int r = 0; r < 4; ++r) {
          const int m = mb + r;
          const size_t oi = (size_t)m * 256 + n;
          const float y = acc[mt][nt][r] + bv;
          if (mode == 0)      out_b[oi] = f2b(y);
          else if (mode == 3) out_b[oi] = f2b(y / (1.0f + __expf(-y)));
          else                out_f[oi] = extra[oi] + coef[n] * y; // mode 2
        }
      }
    }
  }
}

// ---------------------------------------------------------------------------
// Attention: block = (window, head, 64-query tile), 4 waves.
// Phase1: S = q@k^T * 1/sqrt(32) + maskbias -> bf16 LDS (wave = 64-key slab)
// Phase2: two-pass softmax (unnormalized exp in place, rowsum to LDS)
// Phase3: O = E @ v (v pre-transposed [w][f][token]), scale by 1/rowsum.
// grid (256, 8, 4) x 256 thr.
// ---------------------------------------------------------------------------
__global__ __launch_bounds__(256) void attn256(
    const u16* __restrict__ q, const u16* __restrict__ k,
    const u16* __restrict__ vt, const int* __restrict__ mask,
    u16* __restrict__ out)
{
  __shared__ __align__(16) u16 Sb[64][264];   // +8 pad
  __shared__ float rowsum[64];
  const int w = blockIdx.x, h = blockIdx.y, q0 = blockIdx.z * 64;
  const int t = threadIdx.x;
  const int wave = t >> 6, lane = t & 63;
  const int lrow = lane & 15, lk = (lane >> 4) * 8;
  const size_t base = (size_t)w * 65536;
  const float sc = 0.17677669529663687f; // 1/sqrt(32)
  const f32x4 zero = {0.f, 0.f, 0.f, 0.f};

  // Phase 1
  s16x8 af[4];
  #pragma unroll
  for (int mt = 0; mt < 4; ++mt)
    af[mt] = *(const s16x8*)(q + base + (size_t)(q0 + mt*16 + lrow) * 256 + h*32 + lk);
  const int kb = wave * 64;
  #pragma unroll
  for (int nt = 0; nt < 4; ++nt) {
    const int key = kb + nt*16 + lrow;
    s16x8 bf = *(const s16x8*)(k + base + (size_t)key * 256 + h*32 + lk);
    const float mb = (mask[w * 256 + key] != 0) ? 0.0f : -1e9f;
    #pragma unroll
    for (int mt = 0; mt < 4; ++mt) {
      f32x4 cc = __builtin_amdgcn_mfma_f32_16x16x32_bf16(af[mt], bf, zero, 0, 0, 0);
      #pragma unroll
      for (int r = 0; r < 4; ++r)
        Sb[mt*16 + (lane>>4)*4 + r][key] = f2b(cc[r] * sc + mb);
    }
  }
  __syncthreads();

  // Phase 2: thread handles 64-wide chunk of one row (4 threads/row, same wave)
  {
    const int row = t >> 2, c0 = (t & 3) * 64;
    float vals[64];
    float mx = -3e38f;
    #pragma unroll
    for (int j = 0; j < 8; ++j) {
      s16x8 v8 = *(const s16x8*)(&Sb[row][c0 + j*8]);
      #pragma unroll
      for (int e = 0; e < 8; ++e) { float f = b2f((u16)v8[e]); vals[j*8+e] = f; mx = fmaxf(mx, f); }
    }
    mx = fmaxf(mx, __shfl_xor(mx, 1));
    mx = fmaxf(mx, __shfl_xor(mx, 2));
    float sum = 0.f;
    #pragma unroll
    for (int i = 0; i < 64; ++i) { float e = __expf(vals[i] - mx); vals[i] = e; sum += e; }
    sum += __shfl_xor(sum, 1);
    sum += __shfl_xor(sum, 2);
    if ((t & 3) == 0) rowsum[row] = sum;
    #pragma unroll
    for (int j = 0; j < 8; ++j) {
      s16x8 v8;
      #pragma unroll
      for (int e = 0; e < 8; ++e) v8[e] = (short)f2b(vals[j*8+e]);
      *(s16x8*)(&Sb[row][c0 + j*8]) = v8;
    }
  }
  __syncthreads();

  // Phase 3: wave computes 16 query rows x 32 dims, K=256 keys
  f32x4 o0 = {0.f,0.f,0.f,0.f}, o1 = {0.f,0.f,0.f,0.f};
  #pragma unroll
  for (int kk = 0; kk < 256; kk += 32) {
    s16x8 ef = *(const s16x8*)(&Sb[wave*16 + lrow][kk + lk]);
    const u16* vb = vt + base + (size_t)(h*32) * 256 + kk + lk;
    s16x8 vf0 = *(const s16x8*)(vb + (size_t)lrow * 256);
    s16x8 vf1 = *(const s16x8*)(vb + (size_t)(16 + lrow) * 256);
    o0 = __builtin_amdgcn_mfma_f32_16x16x32_bf16(ef, vf0, o0, 0, 0, 0);
    o1 = __builtin_amdgcn_mfma_f32_16x16x32_bf16(ef, vf1, o1, 0, 0, 0);
  }
  const int mrow = wave*16 + (lane >> 4) * 4;
  #pragma unroll
  for (int r = 0; r < 4; ++r) {
    const float inv = 1.0f / rowsum[mrow + r];
    const size_t oaddr = base + (size_t)(q0 + mrow + r) * 256 + h*32;
    out[oaddr + lrow]      = f2b(o0[r] * inv);
    out[oaddr + 16 + lrow] = f2b(o1[r] * inv);
  }
}

// ---------------------------------------------------------------------------
// mask_update = mask & all(mask over window); write fp32 1.0/0.0. grid 256.
// ---------------------------------------------------------------------------
__global__ __launch_bounds__(256) void maskup(const int* __restrict__ mask,
                                              float* __restrict__ out)
{
  __shared__ int wall[4];
  const int w = blockIdx.x, t = threadIdx.x;
  const int v = (mask[w * 256 + t] != 0) ? 1 : 0;
  const int a = __all(v);
  if ((t & 63) == 0) wall[t >> 6] = a;
  __syncthreads();
  const int allw = wall[0] & wall[1] & wall[2] & wall[3];
  out[w * 256 + t] = (v & allw) ? 1.0f : 0.0f;
}

// ---------------------------------------------------------------------------
extern "C" void kernel_launch(void* const* d_in, const int* in_sizes, int n_in,
                              void* d_out, int out_size, void* d_ws, size_t ws_size,
                              hipStream_t stream)
{
  (void)in_sizes; (void)n_in; (void)out_size; (void)ws_size;
  const float* x    = (const float*)d_in[0];
  const int*   mask = (const int*)d_in[1];
  const float* pos  = (const float*)d_in[2];
  const float* Wemb = (const float*)d_in[3];
  const float* bemb = (const float*)d_in[4];
  const float* ln1g = (const float*)d_in[5];
  const float* ln1b = (const float*)d_in[6];
  const float* Wq   = (const float*)d_in[7];
  const float* bq   = (const float*)d_in[8];
  const float* Wk   = (const float*)d_in[9];
  const float* bk   = (const float*)d_in[10];
  const float* Wv   = (const float*)d_in[11];
  const float* bv   = (const float*)d_in[12];
  const float* Wo   = (const float*)d_in[13];
  const float* bo   = (const float*)d_in[14];
  const float* ln2g = (const float*)d_in[15];
  const float* ln2b = (const float*)d_in[16];
  const float* W1   = (const float*)d_in[17];
  const float* W2   = (const float*)d_in[18];
  const float* gam  = (const float*)d_in[19];
  const float* gml  = (const float*)d_in[20];

  char* ws = (char*)d_ws;
  float* shift = (float*)ws;                       // 256 KB
  float* scale = (float*)(ws + (256 << 10));       // 256 KB
  u16*   wt    = (u16*)(ws + (512 << 10));         // 768 KB (6 x 256x256)
  u16*   b0    = (u16*)(ws + ((size_t)2  << 20));  // xm  -> attn_out
  u16*   b1    = (u16*)(ws + ((size_t)34 << 20));  // q   -> ln2_out
  u16*   b2    = (u16*)(ws + ((size_t)66 << 20));  // k   -> h(silu)
  u16*   b3    = (u16*)(ws + ((size_t)98 << 20));  // vT
  float* outx  = (float*)d_out;                    // also fp32 x1 scratch
  float* outm  = outx + 16777216;

  const u16* WqT = wt;
  const u16* WkT = wt + 65536;
  const u16* WvT = wt + 2 * 65536;
  const u16* WoT = wt + 3 * 65536;
  const u16* W1T = wt + 4 * 65536;
  const u16* W2T = wt + 5 * 65536;

  transpose6<<<dim3(6, 32), 256, 0, stream>>>(Wq, Wk, Wv, Wo, W1, W2, wt);
  film_kernel<<<256, 256, 0, stream>>>(pos, Wemb, bemb, shift, scale);
  ln_kernel<<<16384, 256, 0, stream>>>(x, shift, scale, ln1g, ln1b, b0);
  gemm256<<<dim3(512, 2), 256, 0, stream>>>(b0, WqT, bq, nullptr, nullptr, b1, nullptr, 0);
  gemm256<<<dim3(512, 2), 256, 0, stream>>>(b0, WkT, bk, nullptr, nullptr, b2, nullptr, 0);
  gemm256<<<dim3(512, 2), 256, 0, stream>>>(b0, WvT, bv, nullptr, nullptr, b3, nullptr, 1);
  attn256<<<dim3(256, 8, 4), 256, 0, stream>>>(b1, b2, b3, mask, b0);
  // x1 = x + gamma * (attn_out @ Wo + bo)  -> fp32, stored in d_out x-region
  gemm256<<<dim3(512, 2), 256, 0, stream>>>(b0, WoT, bo, x, gam, nullptr, outx, 2);
  ln_kernel<<<16384, 256, 0, stream>>>(outx, nullptr, nullptr, ln2g, ln2b, b1);
  gemm256<<<dim3(512, 2), 256, 0, stream>>>(b1, W1T, nullptr, nullptr, nullptr, b2, nullptr, 3);
  // x_out = x1 + gamma_mlp * (h @ W2)  -> in-place on d_out
  gemm256<<<dim3(512, 2), 256, 0, stream>>>(b2, W2T, nullptr, outx, gml, nullptr, outx, 2);
  maskup<<<256, 256, 0, stream>>>(mask, outm);
}